// Round 1
// baseline (3323.730 us; speedup 1.0000x reference)
//
#include <hip/hip_runtime.h>

#define NTOK 49
#define DIMC 512
#define NHEAD 16
#define HDIM 32
#define SCALEF 0.17677669529663687f  // 32^-0.5

typedef short s16x8 __attribute__((ext_vector_type(8)));
typedef short s16x4 __attribute__((ext_vector_type(4)));
typedef float f32x4 __attribute__((ext_vector_type(4)));

__device__ __forceinline__ short f2bf(float f){
  unsigned u = __builtin_bit_cast(unsigned, f);
  u += 0x7FFFu + ((u >> 16) & 1u);
  return (short)(u >> 16);
}
__device__ __forceinline__ s16x8 ld8(const short* p){
  s16x4 a = *(const s16x4*)p;
  s16x4 b = *(const s16x4*)(p + 4);
  return __builtin_shufflevector(a, b, 0,1,2,3,4,5,6,7);
}
__device__ __forceinline__ s16x8 ldg8(const short* p){
  return *(const s16x8*)p;
}

// ---------------- weight prep: transpose + fp32->bf16, fold SCALE into Wq/bq ---------------
__global__ void prep_kernel(const float* __restrict__ qkv_w, const float* __restrict__ qkv_b,
                            const float* __restrict__ proj_w,
                            short* __restrict__ wqkv_t, short* __restrict__ wproj_t,
                            float* __restrict__ qkvb_s){
  int tid = blockIdx.x * 256 + threadIdx.x;
  if (tid < 1536*512){
    int oc = tid >> 9, k = tid & 511;
    float v = qkv_w[k*1536 + oc];
    if (oc < 512) v *= SCALEF;            // q-section pre-scaled
    wqkv_t[tid] = f2bf(v);                // wqkv_t[oc][k]
  } else {
    int t = tid - 1536*512;
    int oc = t >> 9, k = t & 511;
    wproj_t[t] = f2bf(proj_w[k*512 + oc]); // wproj_t[oc][k]
  }
  if (tid < 1536){
    float bv = qkv_b[tid];
    if (tid < 512) bv *= SCALEF;
    qkvb_s[tid] = bv;
  }
}

// ---------------- fused window attention ---------------
// LDS layout (dynamic, 159112 B):
//   xs : [49][516] bf16 (50568 B)         staged input tile
//   per-wave scratch w=0..7 (6784 shorts = 13568 B each):
//     qs  [64][36]  (offset 0)     | ps [64][68] aliases qs+ks after S is consumed
//     ks  [64][36]  (offset 2304)  | att [64][36] aliases qs after PV
//     vst [32][68]  (offset 4608)  v stored transposed [d][j], rows j>=49 zeroed
#define XS_STRIDE 516
#define XS_BYTES  (NTOK*XS_STRIDE*2)
#define QS_STRIDE 36
#define PS_STRIDE 68
#define VS_STRIDE 68
#define SCR_SHORTS 6784
#define SMEM_BYTES (XS_BYTES + 8*SCR_SHORTS*2)

__global__ __launch_bounds__(512, 2)
void wattn_kernel(const float* __restrict__ xin, const float* __restrict__ mask,
                  const float* __restrict__ rpb, const float* __restrict__ projb,
                  const short* __restrict__ wqkv, const short* __restrict__ wproj,
                  const float* __restrict__ qkvb, float* __restrict__ out){
  extern __shared__ char smem[];
  short* xs = (short*)smem;
  const int tid = threadIdx.x;
  const int w  = tid >> 6;
  const int l  = tid & 63;
  const int lg = l >> 4;
  const int lr = l & 15;
  const int b  = blockIdx.x;
  const int nw = b & 63;
  const bool is_masked = (nw >= 56) || ((nw & 7) == 7);  // only last window row/col has nonzero mask

  short* scr = (short*)(smem + XS_BYTES) + w * SCR_SHORTS;
  short* qs  = scr;
  short* ks  = scr + 2304;
  short* vst = scr + 4608;
  short* ps  = scr;        // alias (q/k dead once S fragments are in regs)
  short* att = scr;        // alias (P dead once PV fragments are in regs)

  // ---- stage x tile (fp32 -> bf16) ----
  {
    const float4* xg = (const float4*)(xin + (size_t)b * NTOK * DIMC);
    for (int idx = tid; idx < NTOK*128; idx += 512){
      int row = idx >> 7, c4 = idx & 127;
      float4 v = xg[row*128 + c4];
      short* d = xs + row*XS_STRIDE + c4*4;
      d[0] = f2bf(v.x); d[1] = f2bf(v.y); d[2] = f2bf(v.z); d[3] = f2bf(v.w);
    }
  }
  // zero v^T pad rows j=49..63 (so PV over K=64 is exact)
  for (int t = l; t < 32*15; t += 64){
    int dd = t / 15, jj = 49 + t % 15;
    vst[dd*VS_STRIDE + jj] = 0;
  }
  __syncthreads();

  f32x4 oacc[4][4] = {};   // persistent proj accumulator: rows 49(+pad), cols [64w,64w+64)

  for (int rd = 0; rd < 2; ++rd){
    const int h = rd*8 + w;
    const int ocb[6] = { h*32, h*32+16, 512+h*32, 512+h*32+16, 1024+h*32, 1024+h*32+16 };

    // ---- QKV GEMM: (49x512)@(512x96) for this head ----
    f32x4 acc[4][6] = {};
    #pragma unroll 2
    for (int kk = 0; kk < 16; ++kk){
      const int kb = kk*32 + lg*8;
      s16x8 afr[4];
      #pragma unroll
      for (int mt = 0; mt < 4; ++mt){
        afr[mt] = ld8(xs + (16*mt + lr)*XS_STRIDE + kb);
      }
      #pragma unroll
      for (int nt = 0; nt < 6; ++nt){
        s16x8 bfr = ldg8(wqkv + (size_t)(ocb[nt] + lr)*512 + kb);
        #pragma unroll
        for (int mt = 0; mt < 4; ++mt){
          acc[mt][nt] = __builtin_amdgcn_mfma_f32_16x16x32_bf16(afr[mt], bfr, acc[mt][nt], 0, 0, 0);
        }
      }
    }
    float bias[6];
    #pragma unroll
    for (int nt = 0; nt < 6; ++nt) bias[nt] = qkvb[ocb[nt] + lr];
    // scatter q,k (row-major [tok][d]) and v transposed ([d][tok]) to wave scratch
    #pragma unroll
    for (int mt = 0; mt < 4; ++mt){
      #pragma unroll
      for (int r = 0; r < 4; ++r){
        const int row = 16*mt + 4*lg + r;
        qs[row*QS_STRIDE + lr]      = f2bf(acc[mt][0][r] + bias[0]);
        qs[row*QS_STRIDE + 16 + lr] = f2bf(acc[mt][1][r] + bias[1]);
        ks[row*QS_STRIDE + lr]      = f2bf(acc[mt][2][r] + bias[2]);
        ks[row*QS_STRIDE + 16 + lr] = f2bf(acc[mt][3][r] + bias[3]);
        if (row < NTOK){
          vst[lr*VS_STRIDE + row]      = f2bf(acc[mt][4][r] + bias[4]);
          vst[(16+lr)*VS_STRIDE + row] = f2bf(acc[mt][5][r] + bias[5]);
        }
      }
    }
    asm volatile("s_waitcnt lgkmcnt(0)" ::: "memory");

    // ---- S = q k^T (K = 32 = head dim, single MFMA step) ----
    s16x8 qa[4], kb4[4];
    #pragma unroll
    for (int mt = 0; mt < 4; ++mt){ qa[mt]  = ld8(qs + (16*mt + lr)*QS_STRIDE + lg*8); }
    #pragma unroll
    for (int nt = 0; nt < 4; ++nt){ kb4[nt] = ld8(ks + (16*nt + lr)*QS_STRIDE + lg*8); }
    f32x4 sfr[4][4];
    #pragma unroll
    for (int mt = 0; mt < 4; ++mt){
      #pragma unroll
      for (int nt = 0; nt < 4; ++nt){
        f32x4 z = {};
        sfr[mt][nt] = __builtin_amdgcn_mfma_f32_16x16x32_bf16(qa[mt], kb4[nt], z, 0, 0, 0);
      }
    }
    // ---- + rel_pos_bias (+ shift mask), mask pad cols ----
    const float* rb = rpb  + h*2401;
    const float* mk = mask + nw*2401;
    #pragma unroll
    for (int mt = 0; mt < 4; ++mt){
      #pragma unroll
      for (int nt = 0; nt < 4; ++nt){
        const int j = 16*nt + lr;
        #pragma unroll
        for (int r = 0; r < 4; ++r){
          const int i = 16*mt + 4*lg + r;
          float v = sfr[mt][nt][r];
          if (i < NTOK && j < NTOK){
            v += rb[i*49 + j];
            if (is_masked) v += mk[i*49 + j];
          }
          if (j > 48) v = -1e30f;
          sfr[mt][nt][r] = v;
        }
      }
    }
    // ---- row softmax (16-lane butterfly per row group), P stored unnormalized ----
    float invs[4][4];
    #pragma unroll
    for (int mt = 0; mt < 4; ++mt){
      #pragma unroll
      for (int r = 0; r < 4; ++r){
        float m = fmaxf(fmaxf(sfr[mt][0][r], sfr[mt][1][r]), fmaxf(sfr[mt][2][r], sfr[mt][3][r]));
        m = fmaxf(m, __shfl_xor(m, 1));
        m = fmaxf(m, __shfl_xor(m, 2));
        m = fmaxf(m, __shfl_xor(m, 4));
        m = fmaxf(m, __shfl_xor(m, 8));
        float p0 = __expf(sfr[mt][0][r] - m);
        float p1 = __expf(sfr[mt][1][r] - m);
        float p2 = __expf(sfr[mt][2][r] - m);
        float p3 = __expf(sfr[mt][3][r] - m);
        float rs = (p0 + p1) + (p2 + p3);
        rs += __shfl_xor(rs, 1);
        rs += __shfl_xor(rs, 2);
        rs += __shfl_xor(rs, 4);
        rs += __shfl_xor(rs, 8);
        invs[mt][r] = 1.0f / rs;
        const int row = 16*mt + 4*lg + r;
        ps[row*PS_STRIDE + lr]      = f2bf(p0);
        ps[row*PS_STRIDE + 16 + lr] = f2bf(p1);
        ps[row*PS_STRIDE + 32 + lr] = f2bf(p2);
        ps[row*PS_STRIDE + 48 + lr] = f2bf(p3);
      }
    }
    asm volatile("s_waitcnt lgkmcnt(0)" ::: "memory");

    // ---- PV: (49x64)@(64x32), v consumed transposed ----
    s16x8 pa[4][2], vb[2][2];
    #pragma unroll
    for (int mt = 0; mt < 4; ++mt){
      #pragma unroll
      for (int k2 = 0; k2 < 2; ++k2){
        pa[mt][k2] = ld8(ps + (16*mt + lr)*PS_STRIDE + k2*32 + lg*8);
      }
    }
    #pragma unroll
    for (int nt = 0; nt < 2; ++nt){
      #pragma unroll
      for (int k2 = 0; k2 < 2; ++k2){
        vb[nt][k2] = ld8(vst + (16*nt + lr)*VS_STRIDE + k2*32 + lg*8);
      }
    }
    f32x4 po[4][2] = {};
    #pragma unroll
    for (int k2 = 0; k2 < 2; ++k2){
      #pragma unroll
      for (int mt = 0; mt < 4; ++mt){
        #pragma unroll
        for (int nt = 0; nt < 2; ++nt){
          po[mt][nt] = __builtin_amdgcn_mfma_f32_16x16x32_bf16(pa[mt][k2], vb[nt][k2], po[mt][nt], 0, 0, 0);
        }
      }
    }
    asm volatile("s_waitcnt lgkmcnt(0)" ::: "memory");
    // normalized head output -> att [64][36] bf16
    #pragma unroll
    for (int mt = 0; mt < 4; ++mt){
      #pragma unroll
      for (int r = 0; r < 4; ++r){
        const int row = 16*mt + 4*lg + r;
        att[row*QS_STRIDE + lr]      = f2bf(po[mt][0][r] * invs[mt][r]);
        att[row*QS_STRIDE + 16 + lr] = f2bf(po[mt][1][r] * invs[mt][r]);
      }
    }
    __syncthreads();

    // ---- fused proj: rank-32 update per head into persistent accumulator ----
    for (int hh = 0; hh < 8; ++hh){
      const short* slot = (const short*)(smem + XS_BYTES) + hh * SCR_SHORTS;
      const int hp = rd*8 + hh;
      s16x8 aa[4];
      #pragma unroll
      for (int mt = 0; mt < 4; ++mt){ aa[mt] = ld8(slot + (16*mt + lr)*QS_STRIDE + lg*8); }
      #pragma unroll
      for (int nt = 0; nt < 4; ++nt){
        s16x8 bb = ldg8(wproj + (size_t)(64*w + 16*nt + lr)*512 + hp*32 + lg*8);
        #pragma unroll
        for (int mt = 0; mt < 4; ++mt){
          oacc[mt][nt] = __builtin_amdgcn_mfma_f32_16x16x32_bf16(aa[mt], bb, oacc[mt][nt], 0, 0, 0);
        }
      }
    }
    __syncthreads();
  }

  // ---- epilogue: + proj_b, fp32 store (rows < 49 only) ----
  float pb[4];
  #pragma unroll
  for (int nt = 0; nt < 4; ++nt) pb[nt] = projb[64*w + 16*nt + lr];
  float* og = out + (size_t)b * NTOK * DIMC;
  #pragma unroll
  for (int mt = 0; mt < 4; ++mt){
    #pragma unroll
    for (int r = 0; r < 4; ++r){
      const int row = 16*mt + 4*lg + r;
      if (row < NTOK){
        #pragma unroll
        for (int nt = 0; nt < 4; ++nt){
          og[row*DIMC + 64*w + 16*nt + lr] = oacc[mt][nt][r] + pb[nt];
        }
      }
    }
  }
}

extern "C" void kernel_launch(void* const* d_in, const int* in_sizes, int n_in,
                              void* d_out, int out_size, void* d_ws, size_t ws_size,
                              hipStream_t stream){
  (void)in_sizes; (void)n_in; (void)out_size; (void)ws_size;
  const float* xin    = (const float*)d_in[0];
  const float* mask   = (const float*)d_in[1];
  const float* qkv_w  = (const float*)d_in[2];
  const float* qkv_b  = (const float*)d_in[3];
  const float* proj_w = (const float*)d_in[4];
  const float* projb  = (const float*)d_in[5];
  const float* rpb    = (const float*)d_in[6];
  float* out = (float*)d_out;

  short* wqkv_t  = (short*)d_ws;                 // [1536][512] bf16
  short* wproj_t = wqkv_t + 1536*512;            // [512][512] bf16
  float* qkvb_s  = (float*)(wproj_t + 512*512);  // [1536] f32 (q pre-scaled)

  prep_kernel<<<4096, 256, 0, stream>>>(qkv_w, qkv_b, proj_w, wqkv_t, wproj_t, qkvb_s);

  static_assert(SMEM_BYTES <= 160*1024, "LDS budget");
  hipFuncSetAttribute((const void*)wattn_kernel, hipFuncAttributeMaxDynamicSharedMemorySize, SMEM_BYTES);
  wattn_kernel<<<4096, 512, SMEM_BYTES, stream>>>(xin, mask, rpb, projb, wqkv_t, wproj_t, qkvb_s, out);
}